// Round 16
// baseline (388.517 us; speedup 1.0000x reference)
//
#include <hip/hip_runtime.h>
#include <math.h>

#define N_NODES  100000
#define N_FEAT   128
#define N_HID    64
#define N_CLASS  10
#define N_GRAPHS 1000
#define NTILES   1563      // ceil(100000/64)   (pre kernel, 64-node tiles)
#define N_EDGES  1600000
#define BLK_N    128       // gather_mlp tile
#define NT2      782       // ceil(100000/128)
#define HF_BLOCKS 2048
#define CSR_STRIDE 64      // fixed bucket per node; P(deg>=64)~1e-20 @ Poisson(16)
#define EMAX_LDS 32        // staged slots per node; P(deg>32)~1e-4 -> global tail
#define APITCH 72          // bf16 row pitch = 144 B (16B-aligned, 2-way banks)
#define PWPITCH 136        // pre: bf16 row pitch = 272 B for K=128 rows

typedef int iv4 __attribute__((ext_vector_type(4)));
typedef __attribute__((ext_vector_type(8))) __bf16 bf16x8;
typedef __attribute__((ext_vector_type(4))) float f32x4;
typedef __attribute__((ext_vector_type(2))) float f32x2;

// ---- bf16 helpers (LDS MFMA staging + final layer): arithmetic fp32.
__device__ __forceinline__ float bflo(unsigned u) { return __uint_as_float(u << 16); }
__device__ __forceinline__ float bfhi(unsigned u) { return __uint_as_float(u & 0xffff0000u); }
__device__ __forceinline__ unsigned bf_rne(float f) {
    unsigned u = __float_as_uint(f);
    return (u + 0x7fffu + ((u >> 16) & 1u)) >> 16;
}
__device__ __forceinline__ unsigned pack2(float a, float b) {
    return bf_rne(a) | (bf_rne(b) << 16);
}

// ---- fp8 e4m3 pack/unpack via HW converters (2 vals/inst). Self-consistent
// encode+decode (same HW interpretation both ways).
__device__ __forceinline__ unsigned pack_fp8x4(float a, float b, float c, float d) {
    int p = __builtin_amdgcn_cvt_pk_fp8_f32(a, b, 0, false);
    p = __builtin_amdgcn_cvt_pk_fp8_f32(c, d, p, true);
    return (unsigned)p;
}

// ---- pre v14 (proven): MFMA bf16 GEMM, 64-node tile, K=128. Output fp8.
// Serial before hist: overlap falsified 3x (v6/v10/v11).
__global__ __launch_bounds__(256, 4) void pre_kernel(
    const float* __restrict__ x, const float* __restrict__ W,
    const float* __restrict__ b, unsigned* __restrict__ hq)
{
    __shared__ unsigned short xsb[64][PWPITCH];   // x tile bf16; reused for out
    __shared__ unsigned short wsb[64][PWPITCH];   // W^T bf16 [n][k]
    const int tid = threadIdx.x;
    const int n0 = blockIdx.x * 64;

    // stage W^T bf16: idx = k*64+n (coalesced read) -> wsb[n][k]
#pragma unroll
    for (int t = 0; t < 32; ++t) {
        const int idx = t * 256 + tid;   // 0..8191
        wsb[idx & 63][idx >> 6] = (unsigned short)bf_rne(W[idx]);
    }
    // stage x tile bf16: 64 rows x 128 cols (float4 coalesced)
#pragma unroll
    for (int t = 0; t < 8; ++t) {
        const int idx = t * 256 + tid;   // 0..2047 float4 slots (32/row)
        const int m = idx >> 5, c4 = idx & 31;
        float4 v = make_float4(0.f, 0.f, 0.f, 0.f);
        if (n0 + m < N_NODES)
            v = *(const float4*)(x + (size_t)(n0 + m) * N_FEAT + c4 * 4);
        xsb[m][c4 * 4 + 0] = (unsigned short)bf_rne(v.x);
        xsb[m][c4 * 4 + 1] = (unsigned short)bf_rne(v.y);
        xsb[m][c4 * 4 + 2] = (unsigned short)bf_rne(v.z);
        xsb[m][c4 * 4 + 3] = (unsigned short)bf_rne(v.w);
    }
    __syncthreads();

    const int wave = tid >> 6;       // rows wave*16..+15
    const int lane = tid & 63;
    const int lr = lane & 15, lg = lane >> 4;
    const f32x4 vzero = {0.f, 0.f, 0.f, 0.f};
    f32x4 acc[4] = {vzero, vzero, vzero, vzero};
#pragma unroll
    for (int s = 0; s < 4; ++s) {     // K-steps of 32
        const char* ar = (const char*)&xsb[wave * 16 + lr][s * 32] + lg * 16;
        const bf16x8 a0 = *(const bf16x8*)ar;
#pragma unroll
        for (int cb = 0; cb < 4; ++cb) {
            const char* br = (const char*)&wsb[cb * 16 + lr][s * 32] + lg * 16;
            const bf16x8 w0 = *(const bf16x8*)br;
            acc[cb] = __builtin_amdgcn_mfma_f32_16x16x32_bf16(a0, w0, acc[cb], 0, 0, 0);
        }
    }
    __syncthreads();   // all xsb/wsb frag reads done; reuse xsb for output
#pragma unroll
    for (int cb = 0; cb < 4; ++cb) {
        const float bias = b[cb * 16 + lr];
#pragma unroll
        for (int rg = 0; rg < 4; ++rg) {
            const float v = acc[cb][rg] + bias;   // no relu in pre
            xsb[wave * 16 + lg * 4 + rg][cb * 16 + lr] = (unsigned short)bf_rne(v);
        }
    }
    __syncthreads();
    // copy-out fp8 (coalesced u32 per lane)
#pragma unroll
    for (int t = 0; t < 4; ++t) {
        const int idx = t * 256 + tid;   // 0..1023
        const int m = idx >> 4, kv = idx & 15;
        if (n0 + m < N_NODES) {
            const unsigned short* p = &xsb[m][kv * 4];
            hq[(size_t)(n0 + m) * 16 + kv] = pack_fp8x4(
                bflo(p[0]), bflo(p[1]), bflo(p[2]), bflo(p[3]));
        }
    }
}

// ---- hist+fill v15: SINGLE-PASS scan (never tested before). History:
// v0 = 8 serial passes, v2/v3/v12 = 8 concurrent range-groups each scanning
// ALL 1.6M dst (FETCH 70MB = 1.8 TB/s fabric read traffic), v4 = bucketize
// (705us, same-line atomic serialization). Write locality proven irrelevant
// (v0-v3 all 77-86us at 92/79/66MB WRITE). Single-pass keeps atomics spread
// over 100K deg addresses but cuts scan reads 8x -- tests whether the NT
// rescan traffic was contending with atomics in the fabric/L2 queues.
// If unchanged (~77us), the returning-atomic floor is traffic-independent
// and hist is conclusively closed.
__global__ __launch_bounds__(256) void hist_fill_kernel(
    const int* __restrict__ ei, int* __restrict__ deg, int* __restrict__ csr)
{
    const int stride = gridDim.x * blockDim.x;
    const int t0 = blockIdx.x * blockDim.x + threadIdx.x;
    const iv4* dst4 = (const iv4*)(ei + N_EDGES);
    const iv4* src4 = (const iv4*)ei;
    for (int q = t0; q < N_EDGES / 4; q += stride) {
        const iv4 d = dst4[q];
        const iv4 s = src4[q];
        {
            int p = atomicAdd(&deg[d.x], 1);
            if (p < CSR_STRIDE) csr[d.x * CSR_STRIDE + p] = s.x;
        }
        {
            int p = atomicAdd(&deg[d.y], 1);
            if (p < CSR_STRIDE) csr[d.y * CSR_STRIDE + p] = s.y;
        }
        {
            int p = atomicAdd(&deg[d.z], 1);
            if (p < CSR_STRIDE) csr[d.z * CSR_STRIDE + p] = s.z;
        }
        {
            int p = atomicAdd(&deg[d.w], 1);
            if (p < CSR_STRIDE) csr[d.w * CSR_STRIDE + p] = s.w;
        }
    }
}

// ---- fused GIN layer v13 (proven): fp8 gather + MFMA bf16 MLP.
// gather is random-LINE-bound; fp8 row = 64B = one line (half of bf16).
// agg fp32 in regs -> bf16 LDS -> MFMA. FP8OUT: intermediate layers emit
// fp8; final layer emits bf16 for pool_head.
template <bool FP8OUT>
__global__ __launch_bounds__(512, 6) void gather_mlp_kernel(
    const unsigned* __restrict__ hin, unsigned* __restrict__ hq_out,
    uint2* __restrict__ hbf_out,
    const int* __restrict__ csr, const int* __restrict__ deg,
    const float* __restrict__ W1, const float* __restrict__ b1,
    const float* __restrict__ W2, const float* __restrict__ b2)
{
    __shared__ unsigned short asb[BLK_N][APITCH];  // agg/z/h bf16 (+eidx overlap)
    __shared__ unsigned short wsb[N_HID][APITCH];  // W^T bf16 [n][k]
    __shared__ int sdeg[BLK_N];
    const int tid = threadIdx.x;
    const int tx = tid & 15, ty = tid >> 4;   // ty = gather group 0..31
    const int sub = tx;
    const int n0 = blockIdx.x * BLK_N;

    // stage W1^T bf16
#pragma unroll
    for (int t = 0; t < 8; ++t) {
        const int idx = t * 512 + tid;        // 0..4095: k=idx>>6, n=idx&63
        wsb[idx & 63][idx >> 6] = (unsigned short)bf_rne(W1[idx]);
    }
    if (tid < BLK_N) {
        const int node = n0 + tid;
        sdeg[tid] = (node < N_NODES) ? deg[node] : 0;
    }
    // stage edge indices: 32 ints into bytes [0..128) of each asb row
#pragma unroll
    for (int t = 0; t < 2; ++t) {
        const int idx = t * 512 + tid;        // 0..1023 int4 slots
        const int r = idx >> 3, s4 = idx & 7;
        const int node = n0 + r;
        int4 v = make_int4(0, 0, 0, 0);
        if (node < N_NODES)
            v = *(const int4*)(csr + (size_t)node * CSR_STRIDE + s4 * 4);
        *(int4*)((char*)&asb[r][0] + s4 * 16) = v;
    }
    __syncthreads();

    // gather: group ty owns rows ty, ty+32, ty+64, ty+96; pairs (rA, rB=rA+32),
    // 16 row-loads in flight per group. Rows are fp8: one u32 per lane.
    for (int pp = 0; pp < 2; ++pp) {
        const int rA = ty + 64 * pp;
        const int rB = rA + 32;
        const int nodeA = n0 + rA;
        const int nodeB = n0 + rB;
        float aAx = 0.f, aAy = 0.f, aAz = 0.f, aAw = 0.f;
        float bAx = 0.f, bAy = 0.f, bAz = 0.f, bAw = 0.f;
        float aBx = 0.f, aBy = 0.f, aBz = 0.f, aBw = 0.f;
        float bBx = 0.f, bBy = 0.f, bBz = 0.f, bBw = 0.f;
        int nA = 0, nB = 0;
        if (nodeA < N_NODES) {
            nA = sdeg[rA]; nA = nA > CSR_STRIDE ? CSR_STRIDE : nA;
            const unsigned s = hin[(size_t)nodeA * 16 + sub];   // self term
            const f32x2 lo = __builtin_amdgcn_cvt_pk_f32_fp8((int)s, false);
            const f32x2 hi = __builtin_amdgcn_cvt_pk_f32_fp8((int)s, true);
            aAx = lo.x; aAy = lo.y; aAz = hi.x; aAw = hi.y;
        }
        if (nodeB < N_NODES) {
            nB = sdeg[rB]; nB = nB > CSR_STRIDE ? CSR_STRIDE : nB;
            const unsigned s = hin[(size_t)nodeB * 16 + sub];   // self term
            const f32x2 lo = __builtin_amdgcn_cvt_pk_f32_fp8((int)s, false);
            const f32x2 hi = __builtin_amdgcn_cvt_pk_f32_fp8((int)s, true);
            aBx = lo.x; aBy = lo.y; aBz = hi.x; aBw = hi.y;
        }
        const int nnA = nA > EMAX_LDS ? EMAX_LDS : nA;
        const int nnB = nB > EMAX_LDS ? EMAX_LDS : nB;
        const int* epA = (const int*)&asb[rA][0];
        const int* epB = (const int*)&asb[rB][0];
        const int mx = nnA > nnB ? nnA : nnB;
        for (int eb = 0; eb < mx; eb += 8) {
            unsigned rvA[8], rvB[8];
            const bool doA = eb < nnA;
            const bool doB = eb < nnB;
            if (doA) {
#pragma unroll
                for (int u = 0; u < 8; ++u) {
                    const int idx = eb + u;
                    const int cl = idx < nnA ? idx : nnA - 1;  // clamp: slots>=deg poison
                    rvA[u] = hin[(size_t)epA[cl] * 16 + sub];
                }
            }
            if (doB) {
#pragma unroll
                for (int u = 0; u < 8; ++u) {
                    const int idx = eb + u;
                    const int cl = idx < nnB ? idx : nnB - 1;
                    rvB[u] = hin[(size_t)epB[cl] * 16 + sub];
                }
            }
            if (doA) {
#pragma unroll
                for (int u = 0; u < 8; u += 2) {
                    if (eb + u < nnA) {
                        const f32x2 lo = __builtin_amdgcn_cvt_pk_f32_fp8((int)rvA[u], false);
                        const f32x2 hi = __builtin_amdgcn_cvt_pk_f32_fp8((int)rvA[u], true);
                        aAx += lo.x; aAy += lo.y; aAz += hi.x; aAw += hi.y;
                    }
                    if (eb + u + 1 < nnA) {
                        const f32x2 lo = __builtin_amdgcn_cvt_pk_f32_fp8((int)rvA[u + 1], false);
                        const f32x2 hi = __builtin_amdgcn_cvt_pk_f32_fp8((int)rvA[u + 1], true);
                        bAx += lo.x; bAy += lo.y; bAz += hi.x; bAw += hi.y;
                    }
                }
            }
            if (doB) {
#pragma unroll
                for (int u = 0; u < 8; u += 2) {
                    if (eb + u < nnB) {
                        const f32x2 lo = __builtin_amdgcn_cvt_pk_f32_fp8((int)rvB[u], false);
                        const f32x2 hi = __builtin_amdgcn_cvt_pk_f32_fp8((int)rvB[u], true);
                        aBx += lo.x; aBy += lo.y; aBz += hi.x; aBw += hi.y;
                    }
                    if (eb + u + 1 < nnB) {
                        const f32x2 lo = __builtin_amdgcn_cvt_pk_f32_fp8((int)rvB[u + 1], false);
                        const f32x2 hi = __builtin_amdgcn_cvt_pk_f32_fp8((int)rvB[u + 1], true);
                        bBx += lo.x; bBy += lo.y; bBz += hi.x; bBw += hi.y;
                    }
                }
            }
        }
        for (int t = EMAX_LDS; t < nA; ++t) { // rare tail (P~1e-4)
            const int s0 = csr[(size_t)nodeA * CSR_STRIDE + t];
            const unsigned a = hin[(size_t)s0 * 16 + sub];
            const f32x2 lo = __builtin_amdgcn_cvt_pk_f32_fp8((int)a, false);
            const f32x2 hi = __builtin_amdgcn_cvt_pk_f32_fp8((int)a, true);
            aAx += lo.x; aAy += lo.y; aAz += hi.x; aAw += hi.y;
        }
        for (int t = EMAX_LDS; t < nB; ++t) {
            const int s0 = csr[(size_t)nodeB * CSR_STRIDE + t];
            const unsigned a = hin[(size_t)s0 * 16 + sub];
            const f32x2 lo = __builtin_amdgcn_cvt_pk_f32_fp8((int)a, false);
            const f32x2 hi = __builtin_amdgcn_cvt_pk_f32_fp8((int)a, true);
            aBx += lo.x; aBy += lo.y; aBz += hi.x; aBw += hi.y;
        }
        // write agg rows bf16 (overwrites this row's eidx -- reads done)
        *(uint2*)((char*)&asb[rA][0] + sub * 8) = make_uint2(
            pack2(aAx + bAx, aAy + bAy), pack2(aAz + bAz, aAw + bAw));
        *(uint2*)((char*)&asb[rB][0] + sub * 8) = make_uint2(
            pack2(aBx + bBx, aBy + bBy), pack2(aBz + bBz, aBw + bBw));
    }
    __syncthreads();

    // ---- MFMA MLP ----
    const int wave = tid >> 6;            // row-block 0..7
    const int lane = tid & 63;
    const int lr = lane & 15;
    const int lg = lane >> 4;
    const f32x4 vzero = {0.f, 0.f, 0.f, 0.f};

    // GEMM1: z = relu(agg @ W1 + b1)
    f32x4 acc[4] = {vzero, vzero, vzero, vzero};
    {
        const char* ar = (const char*)&asb[wave * 16 + lr][0] + lg * 16;
        const bf16x8 a0 = *(const bf16x8*)ar;
        const bf16x8 a1 = *(const bf16x8*)(ar + 64);
#pragma unroll
        for (int cb = 0; cb < 4; ++cb) {
            const char* br = (const char*)&wsb[cb * 16 + lr][0] + lg * 16;
            const bf16x8 w0 = *(const bf16x8*)br;
            const bf16x8 w1 = *(const bf16x8*)(br + 64);
            acc[cb] = __builtin_amdgcn_mfma_f32_16x16x32_bf16(a0, w0, acc[cb], 0, 0, 0);
            acc[cb] = __builtin_amdgcn_mfma_f32_16x16x32_bf16(a1, w1, acc[cb], 0, 0, 0);
        }
    }
#pragma unroll
    for (int cb = 0; cb < 4; ++cb) {
        const float bias = b1[cb * 16 + lr];
#pragma unroll
        for (int rg = 0; rg < 4; ++rg) {
            const float v = fmaxf(acc[cb][rg] + bias, 0.f);
            asb[wave * 16 + lg * 4 + rg][cb * 16 + lr] = (unsigned short)bf_rne(v);
        }
    }
    __syncthreads();                       // all W1 B-frag reads done
#pragma unroll
    for (int t = 0; t < 8; ++t) {
        const int idx = t * 512 + tid;
        wsb[idx & 63][idx >> 6] = (unsigned short)bf_rne(W2[idx]);
    }
    __syncthreads();

    // GEMM2: h = relu(z @ W2 + b2)
#pragma unroll
    for (int cb = 0; cb < 4; ++cb) acc[cb] = vzero;
    {
        const char* ar = (const char*)&asb[wave * 16 + lr][0] + lg * 16;
        const bf16x8 a0 = *(const bf16x8*)ar;
        const bf16x8 a1 = *(const bf16x8*)(ar + 64);
#pragma unroll
        for (int cb = 0; cb < 4; ++cb) {
            const char* br = (const char*)&wsb[cb * 16 + lr][0] + lg * 16;
            const bf16x8 w0 = *(const bf16x8*)br;
            const bf16x8 w1 = *(const bf16x8*)(br + 64);
            acc[cb] = __builtin_amdgcn_mfma_f32_16x16x32_bf16(a0, w0, acc[cb], 0, 0, 0);
            acc[cb] = __builtin_amdgcn_mfma_f32_16x16x32_bf16(a1, w1, acc[cb], 0, 0, 0);
        }
    }
#pragma unroll
    for (int cb = 0; cb < 4; ++cb) {
        const float bias = b2[cb * 16 + lr];
#pragma unroll
        for (int rg = 0; rg < 4; ++rg) {
            const float v = fmaxf(acc[cb][rg] + bias, 0.f);
            asb[wave * 16 + lg * 4 + rg][cb * 16 + lr] = (unsigned short)bf_rne(v);
        }
    }
    __syncthreads();

    // coalesced copy-out: fp8 (intermediate layers) or bf16 (final layer)
#pragma unroll
    for (int t = 0; t < 4; ++t) {
        const int idx = t * 512 + tid;        // 0..2047
        const int m = idx >> 4, kv = idx & 15;
        if (n0 + m < N_NODES) {
            const uint2 v = *(const uint2*)((const char*)&asb[m][0] + kv * 8);
            if (FP8OUT) {
                hq_out[(size_t)(n0 + m) * 16 + kv] = pack_fp8x4(
                    bflo(v.x), bfhi(v.x), bflo(v.y), bfhi(v.y));
            } else {
                hbf_out[(size_t)(n0 + m) * 16 + kv] = v;
            }
        }
    }
}

// ---- fused pool+head: block per graph; wave 0 finishes post/ro/log_softmax
// in-register from the pooled row. Final h is bf16. ----
__global__ __launch_bounds__(256) void pool_head_kernel(
    const unsigned short* __restrict__ h, const int* __restrict__ batch,
    const float* __restrict__ Wp, const float* __restrict__ bp,
    const float* __restrict__ Wr, const float* __restrict__ br,
    float* __restrict__ out)
{
    const int graph = blockIdx.x;
    int l = 0, r = N_NODES;
    while (l < r) { int m = (l + r) >> 1; if (batch[m] < graph) l = m + 1; else r = m; }
    const int lo = l;
    r = N_NODES;
    while (l < r) { int m = (l + r) >> 1; if (batch[m] < graph + 1) l = m + 1; else r = m; }
    const int hi = l;

    const int lane = threadIdx.x & 63;
    const int wave = threadIdx.x >> 6;
    float acc = 0.0f;
    for (int i = lo + wave; i < hi; i += 4)
        acc += __uint_as_float(((unsigned)h[(size_t)i * N_HID + lane]) << 16);
    __shared__ float sacc[4][N_HID];
    sacc[wave][lane] = acc;
    __syncthreads();
    if (wave != 0) return;

    const float gv = sacc[0][lane] + sacc[1][lane] + sacc[2][lane] + sacc[3][lane];
    float acc2 = bp[lane];
#pragma unroll
    for (int k = 0; k < N_HID; ++k) {
        const float gk = __int_as_float(
            __builtin_amdgcn_readlane(__float_as_int(gv), k));
        acc2 = fmaf(gk, Wp[k * N_HID + lane], acc2);
    }
    const float y = fmaxf(acc2, 0.f);

    float logit = (lane < N_CLASS) ? br[lane] : 0.f;
#pragma unroll
    for (int k = 0; k < N_HID; ++k) {
        const float yk = __int_as_float(
            __builtin_amdgcn_readlane(__float_as_int(y), k));
        if (lane < N_CLASS)
            logit = fmaf(yk, Wr[k * N_CLASS + lane], logit);
    }

    __shared__ float slog[N_CLASS];
    if (lane < N_CLASS) slog[lane] = logit;
    if (lane < N_CLASS) {
        float m = -INFINITY;
#pragma unroll
        for (int c = 0; c < N_CLASS; ++c) m = fmaxf(m, slog[c]);
        float sum = 0.0f;
#pragma unroll
        for (int c = 0; c < N_CLASS; ++c) sum += expf(slog[c] - m);
        out[(size_t)graph * N_CLASS + lane] = logit - m - logf(sum);
    }
}

extern "C" void kernel_launch(void* const* d_in, const int* in_sizes, int n_in,
                              void* d_out, int out_size, void* d_ws, size_t ws_size,
                              hipStream_t stream)
{
    const float* x       = (const float*)d_in[0];
    const int*   ei      = (const int*)d_in[1];   // [2, E]: row0=src, row1=dst
    const int*   batch   = (const int*)d_in[2];
    const float* pre_w   = (const float*)d_in[3];
    const float* pre_b   = (const float*)d_in[4];
    const float* conv_w1 = (const float*)d_in[5];
    const float* conv_b1 = (const float*)d_in[6];
    const float* conv_w2 = (const float*)d_in[7];
    const float* conv_b2 = (const float*)d_in[8];
    const float* post_w  = (const float*)d_in[9];
    const float* post_b  = (const float*)d_in[10];
    const float* ro_w    = (const float*)d_in[11];
    const float* ro_b    = (const float*)d_in[12];
    float* out = (float*)d_out;

    // workspace layout (~51.6 MB)
    unsigned* hq0 = (unsigned*)d_ws;                    // 6.4 MB (fp8 h, 64B rows)
    unsigned* hq1 = hq0 + (size_t)N_NODES * 16;         // 6.4 MB
    uint2*    hbf = (uint2*)(hq1 + (size_t)N_NODES * 16); // 12.8 MB (bf16 final h)
    int*      deg = (int*)(hbf + (size_t)N_NODES * 16); // 400 KB
    int*      csr = deg + N_NODES;                      // 25.6 MB fixed-stride

    (void)hipMemsetAsync(deg, 0, N_NODES * sizeof(int), stream);

    pre_kernel<<<NTILES, 256, 0, stream>>>(x, pre_w, pre_b, hq0);
    hist_fill_kernel<<<HF_BLOCKS, 256, 0, stream>>>(ei, deg, csr);

    // 3 fused GIN layers: fp8 ping-pong hq0 -> hq1 -> hq0; final -> bf16 hbf
    gather_mlp_kernel<true><<<NT2, 512, 0, stream>>>(
        hq0, hq1, (uint2*)nullptr, csr, deg,
        conv_w1, conv_b1, conv_w2, conv_b2);
    gather_mlp_kernel<true><<<NT2, 512, 0, stream>>>(
        hq1, hq0, (uint2*)nullptr, csr, deg,
        conv_w1 + N_HID * N_HID, conv_b1 + N_HID,
        conv_w2 + N_HID * N_HID, conv_b2 + N_HID);
    gather_mlp_kernel<false><<<NT2, 512, 0, stream>>>(
        hq0, (unsigned*)nullptr, hbf, csr, deg,
        conv_w1 + 2 * N_HID * N_HID, conv_b1 + 2 * N_HID,
        conv_w2 + 2 * N_HID * N_HID, conv_b2 + 2 * N_HID);

    pool_head_kernel<<<N_GRAPHS, 256, 0, stream>>>(
        (const unsigned short*)hbf, batch, post_w, post_b, ro_w, ro_b, out);
}

// Round 17
// 329.695 us; speedup vs baseline: 1.1784x; 1.1784x over previous
//
#include <hip/hip_runtime.h>
#include <math.h>

#define N_NODES  100000
#define N_FEAT   128
#define N_HID    64
#define N_CLASS  10
#define N_GRAPHS 1000
#define NTILES   1563      // ceil(100000/64)   (pre kernel, 64-node tiles)
#define N_EDGES  1600000
#define BLK_N    128       // gather_mlp tile
#define NT2      782       // ceil(100000/128)
#define HF_GROUPS 8        // concurrent dst ranges
#define HF_RANGE 12500     // 100000/8
#define HF_BLOCKS 2048
#define CSR_STRIDE 64      // fixed bucket per node; P(deg>=64)~1e-20 @ Poisson(16)
#define EMAX_LDS 32        // staged slots per node; P(deg>32)~1e-4 -> global tail
#define APITCH 72          // bf16 row pitch = 144 B (16B-aligned, 2-way banks)
#define PWPITCH 136        // pre: bf16 row pitch = 272 B for K=128 rows

typedef int iv4 __attribute__((ext_vector_type(4)));
typedef __attribute__((ext_vector_type(8))) __bf16 bf16x8;
typedef __attribute__((ext_vector_type(4))) float f32x4;
typedef __attribute__((ext_vector_type(2))) float f32x2;

// ---- bf16 helpers (LDS MFMA staging + final layer): arithmetic fp32.
__device__ __forceinline__ float bflo(unsigned u) { return __uint_as_float(u << 16); }
__device__ __forceinline__ float bfhi(unsigned u) { return __uint_as_float(u & 0xffff0000u); }
__device__ __forceinline__ unsigned bf_rne(float f) {
    unsigned u = __float_as_uint(f);
    return (u + 0x7fffu + ((u >> 16) & 1u)) >> 16;
}
__device__ __forceinline__ unsigned pack2(float a, float b) {
    return bf_rne(a) | (bf_rne(b) << 16);
}

// ---- fp8 e4m3 pack/unpack via HW converters (2 vals/inst). Self-consistent
// encode+decode (same HW interpretation both ways).
__device__ __forceinline__ unsigned pack_fp8x4(float a, float b, float c, float d) {
    int p = __builtin_amdgcn_cvt_pk_fp8_f32(a, b, 0, false);
    p = __builtin_amdgcn_cvt_pk_fp8_f32(c, d, p, true);
    return (unsigned)p;
}

// ---- pre v14 (proven): MFMA bf16 GEMM, 64-node tile, K=128. Output fp8.
// Serial before hist: overlap falsified 3x (v6/v10/v11).
__global__ __launch_bounds__(256, 4) void pre_kernel(
    const float* __restrict__ x, const float* __restrict__ W,
    const float* __restrict__ b, unsigned* __restrict__ hq)
{
    __shared__ unsigned short xsb[64][PWPITCH];   // x tile bf16; reused for out
    __shared__ unsigned short wsb[64][PWPITCH];   // W^T bf16 [n][k]
    const int tid = threadIdx.x;
    const int n0 = blockIdx.x * 64;

    // stage W^T bf16: idx = k*64+n (coalesced read) -> wsb[n][k]
#pragma unroll
    for (int t = 0; t < 32; ++t) {
        const int idx = t * 256 + tid;   // 0..8191
        wsb[idx & 63][idx >> 6] = (unsigned short)bf_rne(W[idx]);
    }
    // stage x tile bf16: 64 rows x 128 cols (float4 coalesced)
#pragma unroll
    for (int t = 0; t < 8; ++t) {
        const int idx = t * 256 + tid;   // 0..2047 float4 slots (32/row)
        const int m = idx >> 5, c4 = idx & 31;
        float4 v = make_float4(0.f, 0.f, 0.f, 0.f);
        if (n0 + m < N_NODES)
            v = *(const float4*)(x + (size_t)(n0 + m) * N_FEAT + c4 * 4);
        xsb[m][c4 * 4 + 0] = (unsigned short)bf_rne(v.x);
        xsb[m][c4 * 4 + 1] = (unsigned short)bf_rne(v.y);
        xsb[m][c4 * 4 + 2] = (unsigned short)bf_rne(v.z);
        xsb[m][c4 * 4 + 3] = (unsigned short)bf_rne(v.w);
    }
    __syncthreads();

    const int wave = tid >> 6;       // rows wave*16..+15
    const int lane = tid & 63;
    const int lr = lane & 15, lg = lane >> 4;
    const f32x4 vzero = {0.f, 0.f, 0.f, 0.f};
    f32x4 acc[4] = {vzero, vzero, vzero, vzero};
#pragma unroll
    for (int s = 0; s < 4; ++s) {     // K-steps of 32
        const char* ar = (const char*)&xsb[wave * 16 + lr][s * 32] + lg * 16;
        const bf16x8 a0 = *(const bf16x8*)ar;
#pragma unroll
        for (int cb = 0; cb < 4; ++cb) {
            const char* br = (const char*)&wsb[cb * 16 + lr][s * 32] + lg * 16;
            const bf16x8 w0 = *(const bf16x8*)br;
            acc[cb] = __builtin_amdgcn_mfma_f32_16x16x32_bf16(a0, w0, acc[cb], 0, 0, 0);
        }
    }
    __syncthreads();   // all xsb/wsb frag reads done; reuse xsb for output
#pragma unroll
    for (int cb = 0; cb < 4; ++cb) {
        const float bias = b[cb * 16 + lr];
#pragma unroll
        for (int rg = 0; rg < 4; ++rg) {
            const float v = acc[cb][rg] + bias;   // no relu in pre
            xsb[wave * 16 + lg * 4 + rg][cb * 16 + lr] = (unsigned short)bf_rne(v);
        }
    }
    __syncthreads();
    // copy-out fp8 (coalesced u32 per lane)
#pragma unroll
    for (int t = 0; t < 4; ++t) {
        const int idx = t * 256 + tid;   // 0..1023
        const int m = idx >> 4, kv = idx & 15;
        if (n0 + m < N_NODES) {
            const unsigned short* p = &xsb[m][kv * 4];
            hq[(size_t)(n0 + m) * 16 + kv] = pack_fp8x4(
                bflo(p[0]), bflo(p[1]), bflo(p[2]), bflo(p[3]));
        }
    }
}

// ---- hist+fill (v3 config, the 77us floor): 8 concurrent dst-ranges with
// XCD affinity, NT dst+src reads, atomics spread over 100K deg addresses.
// CONCLUSIVELY CLOSED after 6 falsifications: serial-8pass 86; this 77;
// write-pattern variants 77-86 (92/79/66MB WRITE); bucketize (few-line
// atomics) 705; line-padded deg 87-89; single-pass 145-152 (v15: no range
// partitioning -> cross-XCD atomic latency fully exposed, no loop to hide
// it). The 8-range structure IS the source of deg/csr L2 locality.
__global__ __launch_bounds__(256) void hist_fill_kernel(
    const int* __restrict__ ei, int* __restrict__ deg, int* __restrict__ csr)
{
    const int r   = blockIdx.x & (HF_GROUPS - 1);
    const int g   = blockIdx.x >> 3;
    const int lo  = r * HF_RANGE;
    const int hi  = lo + HF_RANGE;
    const int gsz = (gridDim.x >> 3) * blockDim.x;
    const int t0  = g * blockDim.x + threadIdx.x;
    const iv4* dst4 = (const iv4*)(ei + N_EDGES);
    for (int q = t0; q < N_EDGES / 4; q += gsz) {
        const iv4 d = __builtin_nontemporal_load(dst4 + q);
        const int e0 = q * 4;
        if (d.x >= lo && d.x < hi) {
            int p = atomicAdd(&deg[d.x], 1);
            if (p < CSR_STRIDE)
                csr[d.x * CSR_STRIDE + p] = __builtin_nontemporal_load(ei + e0);
        }
        if (d.y >= lo && d.y < hi) {
            int p = atomicAdd(&deg[d.y], 1);
            if (p < CSR_STRIDE)
                csr[d.y * CSR_STRIDE + p] = __builtin_nontemporal_load(ei + e0 + 1);
        }
        if (d.z >= lo && d.z < hi) {
            int p = atomicAdd(&deg[d.z], 1);
            if (p < CSR_STRIDE)
                csr[d.z * CSR_STRIDE + p] = __builtin_nontemporal_load(ei + e0 + 2);
        }
        if (d.w >= lo && d.w < hi) {
            int p = atomicAdd(&deg[d.w], 1);
            if (p < CSR_STRIDE)
                csr[d.w * CSR_STRIDE + p] = __builtin_nontemporal_load(ei + e0 + 3);
        }
    }
}

// ---- fused GIN layer v13 (proven): fp8 gather + MFMA bf16 MLP.
// gather is random-LINE-bound; fp8 row = 64B = one line (half of bf16).
// agg fp32 in regs -> bf16 LDS -> MFMA. FP8OUT: intermediate layers emit
// fp8; final layer emits bf16 for pool_head.
template <bool FP8OUT>
__global__ __launch_bounds__(512, 6) void gather_mlp_kernel(
    const unsigned* __restrict__ hin, unsigned* __restrict__ hq_out,
    uint2* __restrict__ hbf_out,
    const int* __restrict__ csr, const int* __restrict__ deg,
    const float* __restrict__ W1, const float* __restrict__ b1,
    const float* __restrict__ W2, const float* __restrict__ b2)
{
    __shared__ unsigned short asb[BLK_N][APITCH];  // agg/z/h bf16 (+eidx overlap)
    __shared__ unsigned short wsb[N_HID][APITCH];  // W^T bf16 [n][k]
    __shared__ int sdeg[BLK_N];
    const int tid = threadIdx.x;
    const int tx = tid & 15, ty = tid >> 4;   // ty = gather group 0..31
    const int sub = tx;
    const int n0 = blockIdx.x * BLK_N;

    // stage W1^T bf16
#pragma unroll
    for (int t = 0; t < 8; ++t) {
        const int idx = t * 512 + tid;        // 0..4095: k=idx>>6, n=idx&63
        wsb[idx & 63][idx >> 6] = (unsigned short)bf_rne(W1[idx]);
    }
    if (tid < BLK_N) {
        const int node = n0 + tid;
        sdeg[tid] = (node < N_NODES) ? deg[node] : 0;
    }
    // stage edge indices: 32 ints into bytes [0..128) of each asb row
#pragma unroll
    for (int t = 0; t < 2; ++t) {
        const int idx = t * 512 + tid;        // 0..1023 int4 slots
        const int r = idx >> 3, s4 = idx & 7;
        const int node = n0 + r;
        int4 v = make_int4(0, 0, 0, 0);
        if (node < N_NODES)
            v = *(const int4*)(csr + (size_t)node * CSR_STRIDE + s4 * 4);
        *(int4*)((char*)&asb[r][0] + s4 * 16) = v;
    }
    __syncthreads();

    // gather: group ty owns rows ty, ty+32, ty+64, ty+96; pairs (rA, rB=rA+32),
    // 16 row-loads in flight per group. Rows are fp8: one u32 per lane.
    for (int pp = 0; pp < 2; ++pp) {
        const int rA = ty + 64 * pp;
        const int rB = rA + 32;
        const int nodeA = n0 + rA;
        const int nodeB = n0 + rB;
        float aAx = 0.f, aAy = 0.f, aAz = 0.f, aAw = 0.f;
        float bAx = 0.f, bAy = 0.f, bAz = 0.f, bAw = 0.f;
        float aBx = 0.f, aBy = 0.f, aBz = 0.f, aBw = 0.f;
        float bBx = 0.f, bBy = 0.f, bBz = 0.f, bBw = 0.f;
        int nA = 0, nB = 0;
        if (nodeA < N_NODES) {
            nA = sdeg[rA]; nA = nA > CSR_STRIDE ? CSR_STRIDE : nA;
            const unsigned s = hin[(size_t)nodeA * 16 + sub];   // self term
            const f32x2 lo = __builtin_amdgcn_cvt_pk_f32_fp8((int)s, false);
            const f32x2 hi = __builtin_amdgcn_cvt_pk_f32_fp8((int)s, true);
            aAx = lo.x; aAy = lo.y; aAz = hi.x; aAw = hi.y;
        }
        if (nodeB < N_NODES) {
            nB = sdeg[rB]; nB = nB > CSR_STRIDE ? CSR_STRIDE : nB;
            const unsigned s = hin[(size_t)nodeB * 16 + sub];   // self term
            const f32x2 lo = __builtin_amdgcn_cvt_pk_f32_fp8((int)s, false);
            const f32x2 hi = __builtin_amdgcn_cvt_pk_f32_fp8((int)s, true);
            aBx = lo.x; aBy = lo.y; aBz = hi.x; aBw = hi.y;
        }
        const int nnA = nA > EMAX_LDS ? EMAX_LDS : nA;
        const int nnB = nB > EMAX_LDS ? EMAX_LDS : nB;
        const int* epA = (const int*)&asb[rA][0];
        const int* epB = (const int*)&asb[rB][0];
        const int mx = nnA > nnB ? nnA : nnB;
        for (int eb = 0; eb < mx; eb += 8) {
            unsigned rvA[8], rvB[8];
            const bool doA = eb < nnA;
            const bool doB = eb < nnB;
            if (doA) {
#pragma unroll
                for (int u = 0; u < 8; ++u) {
                    const int idx = eb + u;
                    const int cl = idx < nnA ? idx : nnA - 1;  // clamp: slots>=deg poison
                    rvA[u] = hin[(size_t)epA[cl] * 16 + sub];
                }
            }
            if (doB) {
#pragma unroll
                for (int u = 0; u < 8; ++u) {
                    const int idx = eb + u;
                    const int cl = idx < nnB ? idx : nnB - 1;
                    rvB[u] = hin[(size_t)epB[cl] * 16 + sub];
                }
            }
            if (doA) {
#pragma unroll
                for (int u = 0; u < 8; u += 2) {
                    if (eb + u < nnA) {
                        const f32x2 lo = __builtin_amdgcn_cvt_pk_f32_fp8((int)rvA[u], false);
                        const f32x2 hi = __builtin_amdgcn_cvt_pk_f32_fp8((int)rvA[u], true);
                        aAx += lo.x; aAy += lo.y; aAz += hi.x; aAw += hi.y;
                    }
                    if (eb + u + 1 < nnA) {
                        const f32x2 lo = __builtin_amdgcn_cvt_pk_f32_fp8((int)rvA[u + 1], false);
                        const f32x2 hi = __builtin_amdgcn_cvt_pk_f32_fp8((int)rvA[u + 1], true);
                        bAx += lo.x; bAy += lo.y; bAz += hi.x; bAw += hi.y;
                    }
                }
            }
            if (doB) {
#pragma unroll
                for (int u = 0; u < 8; u += 2) {
                    if (eb + u < nnB) {
                        const f32x2 lo = __builtin_amdgcn_cvt_pk_f32_fp8((int)rvB[u], false);
                        const f32x2 hi = __builtin_amdgcn_cvt_pk_f32_fp8((int)rvB[u], true);
                        aBx += lo.x; aBy += lo.y; aBz += hi.x; aBw += hi.y;
                    }
                    if (eb + u + 1 < nnB) {
                        const f32x2 lo = __builtin_amdgcn_cvt_pk_f32_fp8((int)rvB[u + 1], false);
                        const f32x2 hi = __builtin_amdgcn_cvt_pk_f32_fp8((int)rvB[u + 1], true);
                        bBx += lo.x; bBy += lo.y; bBz += hi.x; bBw += hi.y;
                    }
                }
            }
        }
        for (int t = EMAX_LDS; t < nA; ++t) { // rare tail (P~1e-4)
            const int s0 = csr[(size_t)nodeA * CSR_STRIDE + t];
            const unsigned a = hin[(size_t)s0 * 16 + sub];
            const f32x2 lo = __builtin_amdgcn_cvt_pk_f32_fp8((int)a, false);
            const f32x2 hi = __builtin_amdgcn_cvt_pk_f32_fp8((int)a, true);
            aAx += lo.x; aAy += lo.y; aAz += hi.x; aAw += hi.y;
        }
        for (int t = EMAX_LDS; t < nB; ++t) {
            const int s0 = csr[(size_t)nodeB * CSR_STRIDE + t];
            const unsigned a = hin[(size_t)s0 * 16 + sub];
            const f32x2 lo = __builtin_amdgcn_cvt_pk_f32_fp8((int)a, false);
            const f32x2 hi = __builtin_amdgcn_cvt_pk_f32_fp8((int)a, true);
            aBx += lo.x; aBy += lo.y; aBz += hi.x; aBw += hi.y;
        }
        // write agg rows bf16 (overwrites this row's eidx -- reads done)
        *(uint2*)((char*)&asb[rA][0] + sub * 8) = make_uint2(
            pack2(aAx + bAx, aAy + bAy), pack2(aAz + bAz, aAw + bAw));
        *(uint2*)((char*)&asb[rB][0] + sub * 8) = make_uint2(
            pack2(aBx + bBx, aBy + bBy), pack2(aBz + bBz, aBw + bBw));
    }
    __syncthreads();

    // ---- MFMA MLP ----
    const int wave = tid >> 6;            // row-block 0..7
    const int lane = tid & 63;
    const int lr = lane & 15;
    const int lg = lane >> 4;
    const f32x4 vzero = {0.f, 0.f, 0.f, 0.f};

    // GEMM1: z = relu(agg @ W1 + b1)
    f32x4 acc[4] = {vzero, vzero, vzero, vzero};
    {
        const char* ar = (const char*)&asb[wave * 16 + lr][0] + lg * 16;
        const bf16x8 a0 = *(const bf16x8*)ar;
        const bf16x8 a1 = *(const bf16x8*)(ar + 64);
#pragma unroll
        for (int cb = 0; cb < 4; ++cb) {
            const char* br = (const char*)&wsb[cb * 16 + lr][0] + lg * 16;
            const bf16x8 w0 = *(const bf16x8*)br;
            const bf16x8 w1 = *(const bf16x8*)(br + 64);
            acc[cb] = __builtin_amdgcn_mfma_f32_16x16x32_bf16(a0, w0, acc[cb], 0, 0, 0);
            acc[cb] = __builtin_amdgcn_mfma_f32_16x16x32_bf16(a1, w1, acc[cb], 0, 0, 0);
        }
    }
#pragma unroll
    for (int cb = 0; cb < 4; ++cb) {
        const float bias = b1[cb * 16 + lr];
#pragma unroll
        for (int rg = 0; rg < 4; ++rg) {
            const float v = fmaxf(acc[cb][rg] + bias, 0.f);
            asb[wave * 16 + lg * 4 + rg][cb * 16 + lr] = (unsigned short)bf_rne(v);
        }
    }
    __syncthreads();                       // all W1 B-frag reads done
#pragma unroll
    for (int t = 0; t < 8; ++t) {
        const int idx = t * 512 + tid;
        wsb[idx & 63][idx >> 6] = (unsigned short)bf_rne(W2[idx]);
    }
    __syncthreads();

    // GEMM2: h = relu(z @ W2 + b2)
#pragma unroll
    for (int cb = 0; cb < 4; ++cb) acc[cb] = vzero;
    {
        const char* ar = (const char*)&asb[wave * 16 + lr][0] + lg * 16;
        const bf16x8 a0 = *(const bf16x8*)ar;
        const bf16x8 a1 = *(const bf16x8*)(ar + 64);
#pragma unroll
        for (int cb = 0; cb < 4; ++cb) {
            const char* br = (const char*)&wsb[cb * 16 + lr][0] + lg * 16;
            const bf16x8 w0 = *(const bf16x8*)br;
            const bf16x8 w1 = *(const bf16x8*)(br + 64);
            acc[cb] = __builtin_amdgcn_mfma_f32_16x16x32_bf16(a0, w0, acc[cb], 0, 0, 0);
            acc[cb] = __builtin_amdgcn_mfma_f32_16x16x32_bf16(a1, w1, acc[cb], 0, 0, 0);
        }
    }
#pragma unroll
    for (int cb = 0; cb < 4; ++cb) {
        const float bias = b2[cb * 16 + lr];
#pragma unroll
        for (int rg = 0; rg < 4; ++rg) {
            const float v = fmaxf(acc[cb][rg] + bias, 0.f);
            asb[wave * 16 + lg * 4 + rg][cb * 16 + lr] = (unsigned short)bf_rne(v);
        }
    }
    __syncthreads();

    // coalesced copy-out: fp8 (intermediate layers) or bf16 (final layer)
#pragma unroll
    for (int t = 0; t < 4; ++t) {
        const int idx = t * 512 + tid;        // 0..2047
        const int m = idx >> 4, kv = idx & 15;
        if (n0 + m < N_NODES) {
            const uint2 v = *(const uint2*)((const char*)&asb[m][0] + kv * 8);
            if (FP8OUT) {
                hq_out[(size_t)(n0 + m) * 16 + kv] = pack_fp8x4(
                    bflo(v.x), bfhi(v.x), bflo(v.y), bfhi(v.y));
            } else {
                hbf_out[(size_t)(n0 + m) * 16 + kv] = v;
            }
        }
    }
}

// ---- fused pool+head: block per graph; wave 0 finishes post/ro/log_softmax
// in-register from the pooled row. Final h is bf16. ----
__global__ __launch_bounds__(256) void pool_head_kernel(
    const unsigned short* __restrict__ h, const int* __restrict__ batch,
    const float* __restrict__ Wp, const float* __restrict__ bp,
    const float* __restrict__ Wr, const float* __restrict__ br,
    float* __restrict__ out)
{
    const int graph = blockIdx.x;
    int l = 0, r = N_NODES;
    while (l < r) { int m = (l + r) >> 1; if (batch[m] < graph) l = m + 1; else r = m; }
    const int lo = l;
    r = N_NODES;
    while (l < r) { int m = (l + r) >> 1; if (batch[m] < graph + 1) l = m + 1; else r = m; }
    const int hi = l;

    const int lane = threadIdx.x & 63;
    const int wave = threadIdx.x >> 6;
    float acc = 0.0f;
    for (int i = lo + wave; i < hi; i += 4)
        acc += __uint_as_float(((unsigned)h[(size_t)i * N_HID + lane]) << 16);
    __shared__ float sacc[4][N_HID];
    sacc[wave][lane] = acc;
    __syncthreads();
    if (wave != 0) return;

    const float gv = sacc[0][lane] + sacc[1][lane] + sacc[2][lane] + sacc[3][lane];
    float acc2 = bp[lane];
#pragma unroll
    for (int k = 0; k < N_HID; ++k) {
        const float gk = __int_as_float(
            __builtin_amdgcn_readlane(__float_as_int(gv), k));
        acc2 = fmaf(gk, Wp[k * N_HID + lane], acc2);
    }
    const float y = fmaxf(acc2, 0.f);

    float logit = (lane < N_CLASS) ? br[lane] : 0.f;
#pragma unroll
    for (int k = 0; k < N_HID; ++k) {
        const float yk = __int_as_float(
            __builtin_amdgcn_readlane(__float_as_int(y), k));
        if (lane < N_CLASS)
            logit = fmaf(yk, Wr[k * N_CLASS + lane], logit);
    }

    __shared__ float slog[N_CLASS];
    if (lane < N_CLASS) slog[lane] = logit;
    if (lane < N_CLASS) {
        float m = -INFINITY;
#pragma unroll
        for (int c = 0; c < N_CLASS; ++c) m = fmaxf(m, slog[c]);
        float sum = 0.0f;
#pragma unroll
        for (int c = 0; c < N_CLASS; ++c) sum += expf(slog[c] - m);
        out[(size_t)graph * N_CLASS + lane] = logit - m - logf(sum);
    }
}

extern "C" void kernel_launch(void* const* d_in, const int* in_sizes, int n_in,
                              void* d_out, int out_size, void* d_ws, size_t ws_size,
                              hipStream_t stream)
{
    const float* x       = (const float*)d_in[0];
    const int*   ei      = (const int*)d_in[1];   // [2, E]: row0=src, row1=dst
    const int*   batch   = (const int*)d_in[2];
    const float* pre_w   = (const float*)d_in[3];
    const float* pre_b   = (const float*)d_in[4];
    const float* conv_w1 = (const float*)d_in[5];
    const float* conv_b1 = (const float*)d_in[6];
    const float* conv_w2 = (const float*)d_in[7];
    const float* conv_b2 = (const float*)d_in[8];
    const float* post_w  = (const float*)d_in[9];
    const float* post_b  = (const float*)d_in[10];
    const float* ro_w    = (const float*)d_in[11];
    const float* ro_b    = (const float*)d_in[12];
    float* out = (float*)d_out;

    // workspace layout (~51.6 MB)
    unsigned* hq0 = (unsigned*)d_ws;                    // 6.4 MB (fp8 h, 64B rows)
    unsigned* hq1 = hq0 + (size_t)N_NODES * 16;         // 6.4 MB
    uint2*    hbf = (uint2*)(hq1 + (size_t)N_NODES * 16); // 12.8 MB (bf16 final h)
    int*      deg = (int*)(hbf + (size_t)N_NODES * 16); // 400 KB
    int*      csr = deg + N_NODES;                      // 25.6 MB fixed-stride

    (void)hipMemsetAsync(deg, 0, N_NODES * sizeof(int), stream);

    pre_kernel<<<NTILES, 256, 0, stream>>>(x, pre_w, pre_b, hq0);
    hist_fill_kernel<<<HF_BLOCKS, 256, 0, stream>>>(ei, deg, csr);

    // 3 fused GIN layers: fp8 ping-pong hq0 -> hq1 -> hq0; final -> bf16 hbf
    gather_mlp_kernel<true><<<NT2, 512, 0, stream>>>(
        hq0, hq1, (uint2*)nullptr, csr, deg,
        conv_w1, conv_b1, conv_w2, conv_b2);
    gather_mlp_kernel<true><<<NT2, 512, 0, stream>>>(
        hq1, hq0, (uint2*)nullptr, csr, deg,
        conv_w1 + N_HID * N_HID, conv_b1 + N_HID,
        conv_w2 + N_HID * N_HID, conv_b2 + N_HID);
    gather_mlp_kernel<false><<<NT2, 512, 0, stream>>>(
        hq0, (unsigned*)nullptr, hbf, csr, deg,
        conv_w1 + 2 * N_HID * N_HID, conv_b1 + 2 * N_HID,
        conv_w2 + 2 * N_HID * N_HID, conv_b2 + 2 * N_HID);

    pool_head_kernel<<<N_GRAPHS, 256, 0, stream>>>(
        (const unsigned short*)hbf, batch, post_w, post_b, ro_w, ro_b, out);
}